// Round 13
// baseline (296.059 us; speedup 1.0000x reference)
//
#include <hip/hip_runtime.h>
#include <hip/hip_fp16.h>
#include <math.h>

// Problem constants (from reference)
#define LL   2048     // seq len
#define BB   64       // batch
#define EE   256      // embedding
#define HH   128      // lstm hidden per dir
#define GG   512      // 4*H gates
#define TT   128      // utterances (L / SEP_EVERY)
#define SEPT 50256

// ---------------------------------------------------------------------------
// Kernel 1: per-column prefix-scan of SEP flags -> seg[t,b], plus per-(utt,b)
// token counts and start offsets (segments are contiguous per column).
// ---------------------------------------------------------------------------
__global__ __launch_bounds__(256) void segscan_k(
    const int* __restrict__ x, int* __restrict__ seg,
    int* __restrict__ cnt, int* __restrict__ start)
{
    int b   = blockIdx.x;    // 0..63
    int tid = threadIdx.x;   // 0..255, 8 tokens each
    __shared__ int tsum[256];
    __shared__ int ucnt[TT];
    __shared__ int ustart[TT];

    int flags[8];
    int local = 0;
#pragma unroll
    for (int i = 0; i < 8; i++) {
        int t = tid * 8 + i;
        flags[i] = (x[t * BB + b] == SEPT) ? 1 : 0;
        local += flags[i];
    }
    tsum[tid] = local;
    __syncthreads();
    int val = local;
    for (int off = 1; off < 256; off <<= 1) {
        int other = (tid >= off) ? tsum[tid - off] : 0;
        __syncthreads();
        val += other;
        tsum[tid] = val;
        __syncthreads();
    }
    int excl = val - local;   // seps strictly before this thread's chunk

    if (tid < TT) ucnt[tid] = 0;
    __syncthreads();
    int run = excl;
#pragma unroll
    for (int i = 0; i < 8; i++) {
        int t = tid * 8 + i;
        int s = run;                 // seg id = #seps before this token
        seg[t * BB + b] = s;
        run += flags[i];
        if (s < TT) atomicAdd(&ucnt[s], 1);
    }
    __syncthreads();
    if (tid == 0) {
        int acc = 0;
        for (int u = 0; u < TT; u++) { ustart[u] = acc; acc += ucnt[u]; }
    }
    __syncthreads();
    if (tid < TT) {
        cnt[tid * BB + b]   = ucnt[tid];
        start[tid * BB + b] = ustart[tid];
    }
}

// ---------------------------------------------------------------------------
// Kernel 2: embedding gather + mean pool. One WAVE per (utt,b); lane holds a
// float4 column slice -> one coalesced 1KB row read per token. Grid = 2048.
// ---------------------------------------------------------------------------
__global__ __launch_bounds__(256) void pool_k(
    const int* __restrict__ x, const float* __restrict__ emb,
    const int* __restrict__ cnt, const int* __restrict__ start,
    float* __restrict__ up)
{
    int wid  = threadIdx.x >> 6;
    int lane = threadIdx.x & 63;
    int bid  = blockIdx.x * 4 + wid;   // u*64+b, bid in [0,8192)
    int b    = bid & 63;
    int c    = cnt[bid];
    int st   = start[bid];

    float4 acc = {0.f, 0.f, 0.f, 0.f};
    int tok = (c > 0) ? x[st * BB + b] : 0;
    for (int j = 0; j < c; j++) {
        int tok_n = (j + 1 < c) ? x[(st + j + 1) * BB + b] : 0;  // prefetch
        float4 v = ((const float4*)(emb + (size_t)tok * EE))[lane];
        acc.x += v.x; acc.y += v.y; acc.z += v.z; acc.w += v.w;
        tok = tok_n;
    }
    float inv = (c > 0) ? 1.f / (float)c : 0.f;
    float4 r = {acc.x * inv, acc.y * inv, acc.z * inv, acc.w * inv};
    ((float4*)(up + (size_t)bid * EE))[lane] = r;
}

// ---------------------------------------------------------------------------
// Kernel 3: xp = u @ W_cat^T + (b_ih + b_hh).  fp32 register-tiled GEMM, v2.
// 128x128 tile, 256 threads, 8x8 micro-tile. Grid (64, 8) = 512 blocks.
// ---------------------------------------------------------------------------
__global__ __launch_bounds__(256) void xp_gemm_k(
    const float* __restrict__ A,
    const float* __restrict__ wf, const float* __restrict__ wb,
    const float* __restrict__ bihf, const float* __restrict__ bhhf,
    const float* __restrict__ bihb, const float* __restrict__ bhhb,
    float* __restrict__ C)
{
    __shared__ float As[32][128];   // [k][m] 16 KB
    __shared__ float Bs[32][128];   // [k][n] 16 KB
    int tid  = threadIdx.x;
    int row0 = blockIdx.x * 128;    // 64 blocks
    int col0 = blockIdx.y * 128;    // 8 blocks
    int tx = tid & 15, ty = tid >> 4;   // 16 x 16 threads, 8x8 micro
    float acc[8][8] = {};

    for (int k0 = 0; k0 < EE; k0 += 32) {
#pragma unroll
        for (int i = 0; i < 4; i++) {
            int idx = tid + i * 256;       // float4 slot, 1024 total
            int m   = idx >> 3;            // 0..127
            int k4  = idx & 7;             // 0..7
            float4 av = *(const float4*)(A + (size_t)(row0 + m) * EE + k0 + k4 * 4);
            As[k4 * 4 + 0][m] = av.x; As[k4 * 4 + 1][m] = av.y;
            As[k4 * 4 + 2][m] = av.z; As[k4 * 4 + 3][m] = av.w;
        }
#pragma unroll
        for (int i = 0; i < 4; i++) {
            int idx = tid + i * 256;
            int n   = idx >> 3;
            int k4  = idx & 7;
            int gc  = col0 + n;
            const float* wsrc = (gc < GG) ? (wf + (size_t)gc * EE)
                                          : (wb + (size_t)(gc - GG) * EE);
            float4 bv = *(const float4*)(wsrc + k0 + k4 * 4);
            Bs[k4 * 4 + 0][n] = bv.x; Bs[k4 * 4 + 1][n] = bv.y;
            Bs[k4 * 4 + 2][n] = bv.z; Bs[k4 * 4 + 3][n] = bv.w;
        }
        __syncthreads();
#pragma unroll
        for (int k = 0; k < 32; k++) {
            float a8[8], b8[8];
            *(float4*)&a8[0] = *(const float4*)&As[k][ty * 8 + 0];
            *(float4*)&a8[4] = *(const float4*)&As[k][ty * 8 + 4];
            *(float4*)&b8[0] = *(const float4*)&Bs[k][tx * 8 + 0];
            *(float4*)&b8[4] = *(const float4*)&Bs[k][tx * 8 + 4];
#pragma unroll
            for (int i = 0; i < 8; i++)
#pragma unroll
                for (int j = 0; j < 8; j++)
                    acc[i][j] += a8[i] * b8[j];
        }
        __syncthreads();
    }

    // epilogue: bias + float4 stores
    float bias[8];
#pragma unroll
    for (int j = 0; j < 8; j++) {
        int gc = col0 + tx * 8 + j;
        bias[j] = (gc < GG) ? (bihf[gc] + bhhf[gc])
                            : (bihb[gc - GG] + bhhb[gc - GG]);
    }
#pragma unroll
    for (int i = 0; i < 8; i++) {
        int r = row0 + ty * 8 + i;
        float4 v0 = {acc[i][0] + bias[0], acc[i][1] + bias[1],
                     acc[i][2] + bias[2], acc[i][3] + bias[3]};
        float4 v1 = {acc[i][4] + bias[4], acc[i][5] + bias[5],
                     acc[i][6] + bias[6], acc[i][7] + bias[7]};
        *(float4*)(C + (size_t)r * 1024 + col0 + tx * 8 + 0) = v0;
        *(float4*)(C + (size_t)r * 1024 + col0 + tx * 8 + 4) = v1;
    }
}

// ---------------------------------------------------------------------------
// Fast activations
// ---------------------------------------------------------------------------
__device__ __forceinline__ float sigm_f(float x) {
    return 1.f / (1.f + __expf(-x));
}
__device__ __forceinline__ float tanh_f(float x) {
    return 1.f - 2.f / (__expf(2.f * x) + 1.f);
}

// ---------------------------------------------------------------------------
// Kernel 3.5: convert W_hh (both dirs) to fp16, octet-major, THREAD-PERMUTED:
// slot p = 4*(g%128) + g/128  (so lstm thread tid=4u+j owns gate j*128+u and
// all its loads stay coalesced: wp[q*512 + tid]).
// o[((dir*16+q)*512 + p)*8 + e] = whh[dir][g][q*8+e]
// ---------------------------------------------------------------------------
__global__ __launch_bounds__(256) void cvt_k(
    const float* __restrict__ wf, const float* __restrict__ wb,
    __half* __restrict__ o)
{
    int i = blockIdx.x * 256 + threadIdx.x;   // 0..131071
    int e   = i & 7;
    int p   = (i >> 3) & 511;    // permuted slot = lstm thread id
    int q   = (i >> 12) & 15;
    int dir = i >> 16;
    int j   = p & 3;
    int u   = p >> 2;
    int g   = j * HH + u;        // gate in natural order
    const float* src = dir ? wb : wf;
    o[i] = __float2half(src[(size_t)g * HH + q * 8 + e]);
}

// v_dot2_f32_f16: c += a.x*b.x + a.y*b.y, fp16 inputs, fp32 accumulate.
typedef _Float16 h2v __attribute__((ext_vector_type(2)));
__device__ __forceinline__ float dot2h(unsigned wbits, unsigned hbits, float c) {
    return __builtin_amdgcn_fdot2(__builtin_bit_cast(h2v, wbits),
                                  __builtin_bit_cast(h2v, hbits), c, false);
}

// ---------------------------------------------------------------------------
// Kernel 4: LSTM recurrence — r24: shfl-fused SINGLE-BARRIER step.
//
// r23 closed the residency chapter (RA scratch-spills even 32 opaque-asm
// regs; neutral). Feed is fixed at 64KB LDS // 64KB L2 per step. The
// remaining attackable cost is the serial TAIL (~500-600 cyc): 2 barriers,
// act[] LDS round-trip, and phase-3 running on only 2 of 8 waves.
//
// r24 structure: thread tid = 4u+j owns gate j*128+u -> a hidden unit's
// 4 gates live in 4 CONSECUTIVE LANES. Each thread activates its own gate
// (single-exp unified form, bit-identical to sigm_f/tanh_f); 3 __shfl_down
// hand f,g,o to the j=0 lane, which does the c/h update — spread over ALL
// 8 waves (16 lanes each) instead of 2. act[] eliminated; h double-buffered
// in LDS -> ONE barrier per step (write goes to hb2[pb^1], reads from
// hb2[pb]; no read/write overlap).
// Per-gate sum order unchanged -> absmax must stay exactly 0.001953125.
// Predicted: step 1827 -> ~1450-1600 cyc; lstm 97.4 -> 78-87 us.
// HARD pre-commit: delta < 5 us -> lstm closed; next rounds = xp_gemm/pool.
// ---------------------------------------------------------------------------
__global__ __launch_bounds__(512, 2) void lstm_rec_k(
    const float* __restrict__ xp,            // [T*B][1024]
    const __half* __restrict__ w16,          // [dir][q][slot][8] permuted
    float* __restrict__ hout)                // [2][T][B][H]
{
    int bid = blockIdx.x;
    int dir = bid >> 6;
    int b   = bid & 63;
    int tid = threadIdx.x;
    int j   = tid & 3;           // gate section: 0:i 1:f 2:g(tanh) 3:o
    int u   = tid >> 2;          // hidden unit 0..127
    int g   = j * HH + u;        // this thread's gate (natural order)
    const uint4* wp = (const uint4*)(w16 + (size_t)dir * (16 * GG * 8));

    __shared__ uint4 wlds[8 * GG];            // octets 0..7, 64 KB, [q][tid]
    __shared__ __align__(16) __half hb2[2][HH];  // h double-buffer (fp16)

    // one-time stage: 64 KB (coalesced: consecutive tids -> consecutive uint4)
#pragma unroll
    for (int t = 0; t < 8; t++) {
        int idx = tid + t * 512;    // = q*512 + tid for q=0..7
        wlds[idx] = wp[idx];
    }

    float c = 0.f;                  // cell state (live in j==0 lanes)
    if (tid < HH) hb2[0][tid] = __float2half(0.f);
    __syncthreads();

    int t0 = dir ? (TT - 1) : 0;
    float xg = xp[(size_t)(t0 * BB + b) * 1024 + dir * GG + g];

    int pb = 0;
    for (int s = 0; s < TT; s++) {
        const uint4* hv = (const uint4*)hb2[pb];   // 16 octets of h

        // ---- full dot for gate g: 8 octets LDS + 8 octets L2 ----
        float acc = xg;             // xp term first (matches prior order)
#pragma unroll
        for (int q = 0; q < 8; q++) {
            uint4 w  = wlds[q * 512 + tid];
            uint4 h4 = hv[q];
            acc = dot2h(w.x, h4.x, acc);
            acc = dot2h(w.y, h4.y, acc);
            acc = dot2h(w.z, h4.z, acc);
            acc = dot2h(w.w, h4.w, acc);
        }
#pragma unroll
        for (int q = 0; q < 8; q++) {
            uint4 w  = wp[(q + 8) * 512 + tid];
            uint4 h4 = hv[q + 8];
            acc = dot2h(w.x, h4.x, acc);
            acc = dot2h(w.y, h4.y, acc);
            acc = dot2h(w.z, h4.z, acc);
            acc = dot2h(w.w, h4.w, acc);
        }

        // ---- activate own gate: one exp, bit-identical to sigm_f/tanh_f ----
        float ex = __expf((j == 2) ? 2.f * acc : -acc);
        float a  = (j == 2) ? (1.f - 2.f / (ex + 1.f)) : (1.f / (1.f + ex));

        // gather f,g,o into the j==0 lane (4 consecutive lanes per unit)
        float a1 = __shfl_down(a, 1);
        float a2 = __shfl_down(a, 2);
        float a3 = __shfl_down(a, 3);

        // prefetch next step's xp while the update runs
        float xg_next = xg;
        if (s < TT - 1) {
            int tn = dir ? (TT - 2 - s) : (s + 1);
            xg_next = xp[(size_t)(tn * BB + b) * 1024 + dir * GG + g];
        }

        // ---- c/h update: all 8 waves, 16 lanes each ----
        if (j == 0) {
            c = a1 * c + a * a2;            // sf*c + si*tg
            float h = a3 * tanh_f(c);       // so * tanh(c)
            hb2[pb ^ 1][u] = __float2half(h);   // write NEXT buffer
            int t = dir ? (TT - 1 - s) : s;
            hout[((size_t)(dir * TT + t) * BB + b) * HH + u] = h;  // fp32 out
        }
        xg = xg_next;
        pb ^= 1;
        __syncthreads();   // ONE barrier: h[pb] now visible for next step
    }
}

// ---------------------------------------------------------------------------
// Kernel 5: head — logits, softmax, argmax, chosen policy. One wave per row.
// ---------------------------------------------------------------------------
__global__ __launch_bounds__(256) void head_k(
    const float* __restrict__ hbuf,           // [2][T][B][H]
    const float* __restrict__ wout, const float* __restrict__ bout,
    float* __restrict__ out)
{
    int wid  = threadIdx.x >> 6;
    int lane = threadIdx.x & 63;
    int row  = blockIdx.x * 4 + wid;          // t*64+b, 0..8191
    int t = row >> 6, b = row & 63;
    const float* hf = hbuf + ((size_t)(t)      * BB + b) * HH;
    const float* hb = hbuf + ((size_t)(TT + t) * BB + b) * HH;

    float l0 = 0.f, l1 = 0.f, v;
    v = hf[lane];      l0 += v * wout[lane];           l1 += v * wout[256 + lane];
    v = hf[lane + 64]; l0 += v * wout[64 + lane];      l1 += v * wout[320 + lane];
    v = hb[lane];      l0 += v * wout[128 + lane];     l1 += v * wout[384 + lane];
    v = hb[lane + 64]; l0 += v * wout[192 + lane];     l1 += v * wout[448 + lane];
#pragma unroll
    for (int off = 32; off > 0; off >>= 1) {
        l0 += __shfl_down(l0, off);
        l1 += __shfl_down(l1, off);
    }
    if (lane == 0) {
        l0 += bout[0]; l1 += bout[1];
        float m  = fmaxf(l0, l1);
        float e0 = __expf(l0 - m), e1 = __expf(l1 - m);
        float inv = 1.f / (e0 + e1);
        float p0 = e0 * inv, p1 = e1 * inv;
        int amax = (l1 > l0) ? 1 : 0;          // tie -> 0, matches jnp.argmax
        out[(size_t)row * 2 + 0] = l0;
        out[(size_t)row * 2 + 1] = l1;
        out[16384 + (size_t)row * 2 + 0] = p0;
        out[16384 + (size_t)row * 2 + 1] = p1;
        out[32768 + row] = amax ? p1 : p0;
        out[40960 + row] = (float)amax;
    }
}

// ---------------------------------------------------------------------------
// Kernel 6: expand utterance mask to tokens, write masked input as float.
// ---------------------------------------------------------------------------
__global__ __launch_bounds__(256) void mask_k(
    const int* __restrict__ x, const int* __restrict__ seg,
    const float* __restrict__ umask, float* __restrict__ out4)
{
    int idx = blockIdx.x * 256 + threadIdx.x;    // < 131072
    int b = idx & 63;
    int s = seg[idx];
    if (s > TT - 1) s = TT - 1;                  // jnp OOB indexing clamps
    if (s < 0) s = 0;
    float keep = umask[s * BB + b];
    out4[idx] = (keep != 0.f) ? (float)x[idx] : 0.f;
}

// ---------------------------------------------------------------------------
extern "C" void kernel_launch(void* const* d_in, const int* in_sizes, int n_in,
                              void* d_out, int out_size, void* d_ws, size_t ws_size,
                              hipStream_t stream)
{
    const int*   x    = (const int*)  d_in[0];
    const float* emb  = (const float*)d_in[1];
    const float* wihf = (const float*)d_in[2];
    const float* whhf = (const float*)d_in[3];
    const float* bihf = (const float*)d_in[4];
    const float* bhhf = (const float*)d_in[5];
    const float* wihb = (const float*)d_in[6];
    const float* whhb = (const float*)d_in[7];
    const float* bihb = (const float*)d_in[8];
    const float* bhhb = (const float*)d_in[9];
    const float* wout = (const float*)d_in[10];
    const float* bout = (const float*)d_in[11];
    float* out = (float*)d_out;
    char*  ws  = (char*)d_ws;

    // workspace layout (bytes)
    int*   seg   = (int*)  (ws + 0);         // 2048*64*4   = 524288
    int*   cnt   = (int*)  (ws + 524288);    // 128*64*4    = 32768
    int*   start = (int*)  (ws + 557056);    // 32768
    float* up    = (float*)(ws + 589824);    // 128*64*256*4  = 8 MB
    float* xp    = (float*)(ws + 8978432);   // 128*64*1024*4 = 32 MB
    float* hbuf  = (float*)(ws + 42532864);  // 2*128*64*128*4 = 8 MB
    // fp16 weight copy lives in the first 256 KB of `up`, which is dead
    // after xp_gemm_k reads it (pool_k regenerates up each iteration).
    __half* wh16 = (__half*)up;

    segscan_k<<<64, 256, 0, stream>>>(x, seg, cnt, start);
    pool_k<<<2048, 256, 0, stream>>>(x, emb, cnt, start, up);   // 8192 waves
    xp_gemm_k<<<dim3(64, 8), 256, 0, stream>>>(up, wihf, wihb, bihf, bhhf, bihb, bhhb, xp);
    cvt_k<<<512, 256, 0, stream>>>(whhf, whhb, wh16);
    lstm_rec_k<<<128, 512, 0, stream>>>(xp, wh16, hbuf);
    head_k<<<2048, 256, 0, stream>>>(hbuf, wout, bout, out);
    mask_k<<<512, 256, 0, stream>>>(x, seg, out + 40960, out + 49152);
}

// Round 15
// 246.436 us; speedup vs baseline: 1.2014x; 1.2014x over previous
//
#include <hip/hip_runtime.h>
#include <hip/hip_fp16.h>
#include <math.h>

// Problem constants (from reference)
#define LL   2048     // seq len
#define BB   64       // batch
#define EE   256      // embedding
#define HH   128      // lstm hidden per dir
#define GG   512      // 4*H gates
#define TT   128      // utterances (L / SEP_EVERY)
#define SEPT 50256

// ---------------------------------------------------------------------------
// Kernel 1: per-column prefix-scan of SEP flags -> seg[t,b], plus per-(utt,b)
// token counts and start offsets (segments are contiguous per column).
// ---------------------------------------------------------------------------
__global__ __launch_bounds__(256) void segscan_k(
    const int* __restrict__ x, int* __restrict__ seg,
    int* __restrict__ cnt, int* __restrict__ start)
{
    int b   = blockIdx.x;    // 0..63
    int tid = threadIdx.x;   // 0..255, 8 tokens each
    __shared__ int tsum[256];
    __shared__ int ucnt[TT];
    __shared__ int ustart[TT];

    int flags[8];
    int local = 0;
#pragma unroll
    for (int i = 0; i < 8; i++) {
        int t = tid * 8 + i;
        flags[i] = (x[t * BB + b] == SEPT) ? 1 : 0;
        local += flags[i];
    }
    tsum[tid] = local;
    __syncthreads();
    int val = local;
    for (int off = 1; off < 256; off <<= 1) {
        int other = (tid >= off) ? tsum[tid - off] : 0;
        __syncthreads();
        val += other;
        tsum[tid] = val;
        __syncthreads();
    }
    int excl = val - local;   // seps strictly before this thread's chunk

    if (tid < TT) ucnt[tid] = 0;
    __syncthreads();
    int run = excl;
#pragma unroll
    for (int i = 0; i < 8; i++) {
        int t = tid * 8 + i;
        int s = run;                 // seg id = #seps before this token
        seg[t * BB + b] = s;
        run += flags[i];
        if (s < TT) atomicAdd(&ucnt[s], 1);
    }
    __syncthreads();
    if (tid == 0) {
        int acc = 0;
        for (int u = 0; u < TT; u++) { ustart[u] = acc; acc += ucnt[u]; }
    }
    __syncthreads();
    if (tid < TT) {
        cnt[tid * BB + b]   = ucnt[tid];
        start[tid * BB + b] = ustart[tid];
    }
}

// ---------------------------------------------------------------------------
// Kernel 2: embedding gather + mean pool (r23 verbatim, fp32 output).
// ---------------------------------------------------------------------------
__global__ __launch_bounds__(256) void pool_k(
    const int* __restrict__ x, const float* __restrict__ emb,
    const int* __restrict__ cnt, const int* __restrict__ start,
    float* __restrict__ up)
{
    int wid  = threadIdx.x >> 6;
    int lane = threadIdx.x & 63;
    int bid  = blockIdx.x * 4 + wid;   // u*64+b, bid in [0,8192)
    int b    = bid & 63;
    int c    = cnt[bid];
    int st   = start[bid];

    float4 acc = {0.f, 0.f, 0.f, 0.f};
    int tok = (c > 0) ? x[st * BB + b] : 0;
    for (int j = 0; j < c; j++) {
        int tok_n = (j + 1 < c) ? x[(st + j + 1) * BB + b] : 0;  // prefetch
        float4 v = ((const float4*)(emb + (size_t)tok * EE))[lane];
        acc.x += v.x; acc.y += v.y; acc.z += v.z; acc.w += v.w;
        tok = tok_n;
    }
    float inv = (c > 0) ? 1.f / (float)c : 0.f;
    float4 r = {acc.x * inv, acc.y * inv, acc.z * inv, acc.w * inv};
    ((float4*)(up + (size_t)bid * EE))[lane] = r;
}

// ---------------------------------------------------------------------------
// Kernel 3: xp = u @ W_cat^T + (b_ih+b_hh) — r26: SPLIT-fp16 MFMA, 3-pass.
//
// r25 forensics: logits PASSED with single-pass fp16 MFMA -> the fragment
// mappings (A row=lane&15,k=(lane>>4)*8+e; B same code on [n][k]; D
// col=lane&15,row=(lane>>4)*4+r) are empirically validated. The failure
// was PRECISION: fp16-quantized u and W_ih added ~4e-4 to xp and flipped a
// near-tie argmax (u_mask flip -> 5e4 in masked_input).
//
// r26: exact two-term split per input — hi=(half)x, lo=(half)(x-hi) — and
// THREE mfma passes (hi*hi + lo*hi + hi*lo; only lo*lo ~2^-22 dropped),
// fp32 accumulate. xp error ~1e-5, 100x below r25, far below the proven
// lstm fp16 error (0.00195). Cost: 12.9 GFLOP at MFMA rate + same staging
// bytes as fp32 -> ~15-25 us vs fp32's 27 us compute floor (measured ~40).
// ---------------------------------------------------------------------------
typedef _Float16 f16x8 __attribute__((ext_vector_type(8)));
typedef float f32x4 __attribute__((ext_vector_type(4)));

__global__ __launch_bounds__(256) void xp_gemm_k(
    const float* __restrict__ A,       // up fp32 [8192][256]
    const float* __restrict__ wf, const float* __restrict__ wb,
    const float* __restrict__ bihf, const float* __restrict__ bhhf,
    const float* __restrict__ bihb, const float* __restrict__ bhhb,
    float* __restrict__ C)             // [8192][1024]
{
    __shared__ _Float16 Ahi[128 * 40];   // row*40 + k (pad 8) = 10 KB each
    __shared__ _Float16 Alo[128 * 40];
    __shared__ _Float16 Bhi[128 * 40];
    __shared__ _Float16 Blo[128 * 40];
    int tid = threadIdx.x;
    int m0 = blockIdx.x * 128;           // 64 blocks
    int n0 = blockIdx.y * 128;           // 8 blocks
    int wave = tid >> 6, l = tid & 63;
    int wm = wave >> 1, wn = wave & 1;   // 2x2 waves, each 64x64
    int lr = l & 15, lk = l >> 4;        // frag non-k index / k-group
    int srow = tid >> 1, shalf = tid & 1;

    f32x4 acc[4][4] = {};

    for (int k0 = 0; k0 < EE; k0 += 32) {
        // ---- stage: load fp32, split hi/lo, store packed to LDS ----
        const float* ga = A + (size_t)(m0 + srow) * EE + k0 + shalf * 16;
        int gc = n0 + srow;
        const float* gw = ((gc < GG) ? (wf + (size_t)gc * EE)
                                     : (wb + (size_t)(gc - GG) * EE))
                          + k0 + shalf * 16;
        float av[16], bv[16];
#pragma unroll
        for (int i = 0; i < 4; i++) {
            *(float4*)&av[i * 4] = *(const float4*)(ga + i * 4);
            *(float4*)&bv[i * 4] = *(const float4*)(gw + i * 4);
        }
        _Float16 ah[16], al[16], bh[16], bl[16];
#pragma unroll
        for (int e = 0; e < 16; e++) {
            _Float16 h = (_Float16)av[e];
            ah[e] = h;  al[e] = (_Float16)(av[e] - (float)h);
            _Float16 hb = (_Float16)bv[e];
            bh[e] = hb; bl[e] = (_Float16)(bv[e] - (float)hb);
        }
        int base = srow * 40 + shalf * 16;   // bytes: srow*80 + shalf*32 (16B-aligned)
        *(uint4*)&Ahi[base]     = *(uint4*)&ah[0];
        *(uint4*)&Ahi[base + 8] = *(uint4*)&ah[8];
        *(uint4*)&Alo[base]     = *(uint4*)&al[0];
        *(uint4*)&Alo[base + 8] = *(uint4*)&al[8];
        *(uint4*)&Bhi[base]     = *(uint4*)&bh[0];
        *(uint4*)&Bhi[base + 8] = *(uint4*)&bh[8];
        *(uint4*)&Blo[base]     = *(uint4*)&bl[0];
        *(uint4*)&Blo[base + 8] = *(uint4*)&bl[8];
        __syncthreads();

        // ---- fragments + 3-pass MFMA ----
        f16x8 bhif[4], blof[4];
#pragma unroll
        for (int nf = 0; nf < 4; nf++) {
            int boff = (wn * 64 + nf * 16 + lr) * 40 + lk * 8;
            bhif[nf] = *(const f16x8*)&Bhi[boff];
            blof[nf] = *(const f16x8*)&Blo[boff];
        }
#pragma unroll
        for (int mf = 0; mf < 4; mf++) {
            int aoff = (wm * 64 + mf * 16 + lr) * 40 + lk * 8;
            f16x8 ahif = *(const f16x8*)&Ahi[aoff];
            f16x8 alof = *(const f16x8*)&Alo[aoff];
#pragma unroll
            for (int nf = 0; nf < 4; nf++) {
                acc[mf][nf] = __builtin_amdgcn_mfma_f32_16x16x32_f16(
                    ahif, bhif[nf], acc[mf][nf], 0, 0, 0);
                acc[mf][nf] = __builtin_amdgcn_mfma_f32_16x16x32_f16(
                    alof, bhif[nf], acc[mf][nf], 0, 0, 0);
                acc[mf][nf] = __builtin_amdgcn_mfma_f32_16x16x32_f16(
                    ahif, blof[nf], acc[mf][nf], 0, 0, 0);
            }
        }
        __syncthreads();
    }

    // epilogue: fp32 bias + stores (layout validated by r25's passing logits)
    float bias[4];
#pragma unroll
    for (int nf = 0; nf < 4; nf++) {
        int gc = n0 + wn * 64 + nf * 16 + lr;
        bias[nf] = (gc < GG) ? (bihf[gc] + bhhf[gc])
                             : (bihb[gc - GG] + bhhb[gc - GG]);
    }
#pragma unroll
    for (int mf = 0; mf < 4; mf++) {
#pragma unroll
        for (int nf = 0; nf < 4; nf++) {
            int n = n0 + wn * 64 + nf * 16 + lr;
#pragma unroll
            for (int r = 0; r < 4; r++) {
                int m = m0 + wm * 64 + mf * 16 + lk * 4 + r;
                C[(size_t)m * 1024 + n] = acc[mf][nf][r] + bias[nf];
            }
        }
    }
}

// ---------------------------------------------------------------------------
// Fast activations
// ---------------------------------------------------------------------------
__device__ __forceinline__ float sigm_f(float x) {
    return 1.f / (1.f + __expf(-x));
}
__device__ __forceinline__ float tanh_f(float x) {
    return 1.f - 2.f / (__expf(2.f * x) + 1.f);
}

// ---------------------------------------------------------------------------
// Kernel 3.5: convert W_hh (both dirs) to fp16 in octet-major layout
// (r23 verbatim): o[((dir*16+q)*512+g)*8+e] = whh[dir][g][q*8+e]
// ---------------------------------------------------------------------------
__global__ __launch_bounds__(256) void cvt_k(
    const float* __restrict__ wf, const float* __restrict__ wb,
    __half* __restrict__ o)
{
    int i = blockIdx.x * 256 + threadIdx.x;   // 0..131071
    int e   = i & 7;
    int g   = (i >> 3) & 511;
    int q   = (i >> 12) & 15;
    int dir = i >> 16;
    const float* src = dir ? wb : wf;
    o[i] = __float2half(src[(size_t)g * HH + q * 8 + e]);
}

// v_dot2_f32_f16: c += a.x*b.x + a.y*b.y, fp16 inputs, fp32 accumulate.
typedef _Float16 h2v __attribute__((ext_vector_type(2)));
__device__ __forceinline__ float dot2h(unsigned wbits, unsigned hbits, float c) {
    return __builtin_amdgcn_fdot2(__builtin_bit_cast(h2v, wbits),
                                  __builtin_bit_cast(h2v, hbits), c, false);
}

// ---------------------------------------------------------------------------
// Kernel 4: LSTM recurrence — r23 VERBATIM (best measured: 97.4 us; lstm
// closed per r24's hard pre-commit).
// ---------------------------------------------------------------------------
__global__ __launch_bounds__(512, 2) void lstm_rec_k(
    const float* __restrict__ xp,            // [T*B][1024]
    const __half* __restrict__ w16,          // [dir][q][gate][8] octet-major
    float* __restrict__ hout)                // [2][T][B][H]
{
    int bid = blockIdx.x;
    int dir = bid >> 6;
    int b   = bid & 63;
    int tid = threadIdx.x;
    int g   = tid;                  // this thread's gate
    int sect = g >> 7;              // 0:i 1:f 2:g 3:o (wave-uniform)
    const uint4* wp = (const uint4*)(w16 + (size_t)dir * (16 * GG * 8));

    __shared__ uint4 wlds[8 * GG];            // octets 0..7, 64 KB, [q][g]
    __shared__ __align__(16) __half h16_lds[HH];
    __shared__ float act[GG];

    // one-time stage: 64 KB (coalesced)
#pragma unroll
    for (int t = 0; t < 8; t++) {
        int idx = tid + t * 512;    // = q*512 + g for q=0..7
        wlds[idx] = wp[idx];
    }

    // one-time load of streamed octets 8..15 (loop-invariant), opaque copy
    uint4 q8[8];
#pragma unroll
    for (int q = 0; q < 8; q++)
        q8[q] = wp[(q + 8) * GG + g];
#pragma unroll
    for (int q = 0; q < 8; q++) {
        asm volatile("" : "+v"(q8[q].x), "+v"(q8[q].y),
                          "+v"(q8[q].z), "+v"(q8[q].w));
    }

    float c = 0.f;                  // cell state (threads < 128)
    if (tid < HH) h16_lds[tid] = __float2half(0.f);
    __syncthreads();

    const uint4* h16v = (const uint4*)h16_lds;   // 16 octets of h

    int t0   = dir ? (TT - 1) : 0;
    float xg = xp[(size_t)(t0 * BB + b) * 1024 + dir * GG + g];

    for (int s = 0; s < TT; s++) {
        // ---- phase 1: full dot for gate g ----
        float acc = xg;             // xp term first
#pragma unroll
        for (int q = 0; q < 8; q++) {
            uint4 w = wlds[q * GG + g];
            uint4 hv = h16v[q];
            acc = dot2h(w.x, hv.x, acc);
            acc = dot2h(w.y, hv.y, acc);
            acc = dot2h(w.z, hv.z, acc);
            acc = dot2h(w.w, hv.w, acc);
        }
#pragma unroll
        for (int q = 0; q < 8; q++) {
            uint4 w = q8[q];
            uint4 hv = h16v[q + 8];
            acc = dot2h(w.x, hv.x, acc);
            acc = dot2h(w.y, hv.y, acc);
            acc = dot2h(w.z, hv.z, acc);
            acc = dot2h(w.w, hv.w, acc);
        }

        act[g] = (sect == 2) ? tanh_f(acc) : sigm_f(acc);

        float xg_next = xg;
        if (s < TT - 1) {
            int tn = dir ? (TT - 2 - s) : (s + 1);
            xg_next = xp[(size_t)(tn * BB + b) * 1024 + dir * GG + g];
        }
        __syncthreads();

        // ---- phase 3: c/h update for hidden unit tid (<128) ----
        if (tid < HH) {
            float si = act[tid], sf = act[HH + tid];
            float tg = act[2 * HH + tid], so = act[3 * HH + tid];
            c = sf * c + si * tg;
            float h = so * tanh_f(c);
            h16_lds[tid] = __float2half(h);   // recurrence input (fp16)
            int t = dir ? (TT - 1 - s) : s;
            hout[((size_t)(dir * TT + t) * BB + b) * HH + tid] = h;  // fp32 out
        }
        xg = xg_next;
        __syncthreads();   // h16/act reuse vs next p1
    }
}

// ---------------------------------------------------------------------------
// Kernel 5: head — logits, softmax, argmax, chosen policy. One wave per row.
// ---------------------------------------------------------------------------
__global__ __launch_bounds__(256) void head_k(
    const float* __restrict__ hbuf,           // [2][T][B][H]
    const float* __restrict__ wout, const float* __restrict__ bout,
    float* __restrict__ out)
{
    int wid  = threadIdx.x >> 6;
    int lane = threadIdx.x & 63;
    int row  = blockIdx.x * 4 + wid;          // t*64+b, 0..8191
    int t = row >> 6, b = row & 63;
    const float* hf = hbuf + ((size_t)(t)      * BB + b) * HH;
    const float* hb = hbuf + ((size_t)(TT + t) * BB + b) * HH;

    float l0 = 0.f, l1 = 0.f, v;
    v = hf[lane];      l0 += v * wout[lane];           l1 += v * wout[256 + lane];
    v = hf[lane + 64]; l0 += v * wout[64 + lane];      l1 += v * wout[320 + lane];
    v = hb[lane];      l0 += v * wout[128 + lane];     l1 += v * wout[384 + lane];
    v = hb[lane + 64]; l0 += v * wout[192 + lane];     l1 += v * wout[448 + lane];
#pragma unroll
    for (int off = 32; off > 0; off >>= 1) {
        l0 += __shfl_down(l0, off);
        l1 += __shfl_down(l1, off);
    }
    if (lane == 0) {
        l0 += bout[0]; l1 += bout[1];
        float m  = fmaxf(l0, l1);
        float e0 = __expf(l0 - m), e1 = __expf(l1 - m);
        float inv = 1.f / (e0 + e1);
        float p0 = e0 * inv, p1 = e1 * inv;
        int amax = (l1 > l0) ? 1 : 0;          // tie -> 0, matches jnp.argmax
        out[(size_t)row * 2 + 0] = l0;
        out[(size_t)row * 2 + 1] = l1;
        out[16384 + (size_t)row * 2 + 0] = p0;
        out[16384 + (size_t)row * 2 + 1] = p1;
        out[32768 + row] = amax ? p1 : p0;
        out[40960 + row] = (float)amax;
    }
}

// ---------------------------------------------------------------------------
// Kernel 6: expand utterance mask to tokens, write masked input as float.
// ---------------------------------------------------------------------------
__global__ __launch_bounds__(256) void mask_k(
    const int* __restrict__ x, const int* __restrict__ seg,
    const float* __restrict__ umask, float* __restrict__ out4)
{
    int idx = blockIdx.x * 256 + threadIdx.x;    // < 131072
    int b = idx & 63;
    int s = seg[idx];
    if (s > TT - 1) s = TT - 1;                  // jnp OOB indexing clamps
    if (s < 0) s = 0;
    float keep = umask[s * BB + b];
    out4[idx] = (keep != 0.f) ? (float)x[idx] : 0.f;
}

// ---------------------------------------------------------------------------
extern "C" void kernel_launch(void* const* d_in, const int* in_sizes, int n_in,
                              void* d_out, int out_size, void* d_ws, size_t ws_size,
                              hipStream_t stream)
{
    const int*   x    = (const int*)  d_in[0];
    const float* emb  = (const float*)d_in[1];
    const float* wihf = (const float*)d_in[2];
    const float* whhf = (const float*)d_in[3];
    const float* bihf = (const float*)d_in[4];
    const float* bhhf = (const float*)d_in[5];
    const float* wihb = (const float*)d_in[6];
    const float* whhb = (const float*)d_in[7];
    const float* bihb = (const float*)d_in[8];
    const float* bhhb = (const float*)d_in[9];
    const float* wout = (const float*)d_in[10];
    const float* bout = (const float*)d_in[11];
    float* out = (float*)d_out;
    char*  ws  = (char*)d_ws;

    // workspace layout (bytes) — r23 layout verbatim
    int*   seg   = (int*)  (ws + 0);         // 524288
    int*   cnt   = (int*)  (ws + 524288);    // 32768
    int*   start = (int*)  (ws + 557056);    // 32768
    float* up    = (float*)(ws + 589824);    // 8192*256*4 = 8 MB
    float* xp    = (float*)(ws + 8978432);   // 32 MB
    float* hbuf  = (float*)(ws + 42532864);  // 8 MB
    // fp16 whh copy lives in the first 256 KB of `up`, dead after xp_gemm_k
    // reads it (cvt_k runs between xp_gemm and lstm; pool_k regenerates up).
    __half* wh16 = (__half*)up;

    segscan_k<<<64, 256, 0, stream>>>(x, seg, cnt, start);
    pool_k<<<2048, 256, 0, stream>>>(x, emb, cnt, start, up);   // 8192 waves
    xp_gemm_k<<<dim3(64, 8), 256, 0, stream>>>(up, wihf, wihb, bihf, bhhf, bihb, bhhb, xp);
    cvt_k<<<512, 256, 0, stream>>>(whhf, whhb, wh16);
    lstm_rec_k<<<128, 512, 0, stream>>>(xp, wh16, hbuf);
    head_k<<<2048, 256, 0, stream>>>(hbuf, wout, bout, out);
    mask_k<<<512, 256, 0, stream>>>(x, seg, out + 40960, out + 49152);
}